// Round 10
// baseline (46.001 us; speedup 1.0000x reference)
//
#include <hip/hip_runtime.h>
#include <stdint.h>
#include <math.h>

// Problem constants (fixed by the reference)
#define BATCH 8
#define HH 2048
#define WW 2048
#define R 8                           // rows per chunk (8 -> 2048 blocks, 8 waves/SIMD)
#define NSTRIPS (HH / R)              // 256
#define NBLK (NSTRIPS * BATCH)        // 2048 chunks == 2048 blocks
#define BLK_WORDS (R * WW / 32)       // 512 mask dwords per chunk
#define MAXK 2000000
#define TAIL_I4 (MAXK / 4)            // 500000 int4 slots per output plane
#define TAIL_PER_BLK ((TAIL_I4 + NBLK - 1) / NBLK)  // 245

// ---------------- Kernel 1: 5x5 local-max mask + per-chunk count -----------
// One block per 8x2048 chunk. Register-rolling separable max; thread owns 8
// consecutive columns + 2-col halo each side (redundant loads hit the same
// cachelines). Bijective XCD swizzle so halo-sharing neighbor strips land on
// the same XCD's L2 (2048 % 8 == 0).
__global__ __launch_bounds__(256) void nms_mask(const float* __restrict__ scores,
                                                uint8_t* __restrict__ maskbytes,
                                                int* __restrict__ counts) {
    // XCD swizzle: blocks b with b%8==x -> contiguous chunk range for XCD x
    const int chunk = (int)(blockIdx.x % 8) * (NBLK / 8) + (int)(blockIdx.x / 8);

    const int tid  = threadIdx.x;
    const int lane = tid & 63;
    const int wv   = tid >> 6;
    const int b     = chunk >> 8;            // / NSTRIPS (=256)
    const int strip = chunk & (NSTRIPS - 1);
    const int h0    = strip * R;
    const int c0    = wv * 512 + lane * 8;   // first owned column
    const float* colp = scores + (size_t)b * HH * WW + c0;
    const bool has_l = (c0 != 0);
    const bool has_r = (c0 != WW - 8);

    float win[5][12];  // columns c0-2 .. c0+9

#define LOAD_ROW(PH, hrow)                                                    \
    do {                                                                      \
        const int h_ = (hrow);                                                \
        if ((unsigned)h_ < (unsigned)HH) {                                    \
            const float* p_ = colp + (size_t)h_ * WW;                         \
            float4 a_ = *(const float4*)(p_);                                 \
            float4 b_ = *(const float4*)(p_ + 4);                             \
            win[PH][2] = a_.x; win[PH][3] = a_.y;                             \
            win[PH][4] = a_.z; win[PH][5] = a_.w;                             \
            win[PH][6] = b_.x; win[PH][7] = b_.y;                             \
            win[PH][8] = b_.z; win[PH][9] = b_.w;                             \
            if (has_l) {                                                      \
                float2 hl_ = *(const float2*)(p_ - 2);                        \
                win[PH][0] = hl_.x; win[PH][1] = hl_.y;                       \
            } else { win[PH][0] = -INFINITY; win[PH][1] = -INFINITY; }        \
            if (has_r) {                                                      \
                float2 hr_ = *(const float2*)(p_ + 8);                        \
                win[PH][10] = hr_.x; win[PH][11] = hr_.y;                     \
            } else { win[PH][10] = -INFINITY; win[PH][11] = -INFINITY; }      \
        } else {                                                              \
            _Pragma("unroll")                                                 \
            for (int k_ = 0; k_ < 12; ++k_) win[PH][k_] = -INFINITY;          \
        }                                                                     \
    } while (0)

    LOAD_ROW(0, h0 - 2);
    LOAD_ROW(1, h0 - 1);
    LOAD_ROW(2, h0 + 0);
    LOAD_ROW(3, h0 + 1);

    int pc = 0;
    size_t outbyte = (((size_t)(b * HH + h0) * WW) + c0) >> 3;

#pragma unroll
    for (int i = 0; i < R; ++i) {
        LOAD_ROW((4 + i) % 5, h0 + 2 + i);
        const int CEN = (2 + i) % 5;

        float v[12];
#pragma unroll
        for (int k = 0; k < 12; ++k)
            v[k] = fmaxf(fmaxf(fmaxf(win[0][k], win[1][k]),
                               fmaxf(win[2][k], win[3][k])), win[4][k]);
        float p[11];
#pragma unroll
        for (int k = 0; k < 11; ++k) p[k] = fmaxf(v[k], v[k + 1]);

        uint32_t byte = 0;
#pragma unroll
        for (int j = 0; j < 8; ++j) {
            const float hm = fmaxf(fmaxf(p[j], p[j + 2]), v[j + 4]);
            const float s  = win[CEN][j + 2];
            if ((s == hm) && (s > 0.0f)) byte |= (1u << j);
        }
        maskbytes[outbyte] = (uint8_t)byte;
        outbyte += WW / 8;
        pc += __popc(byte);
    }
#undef LOAD_ROW

    // fused per-chunk count
#pragma unroll
    for (int d = 32; d >= 1; d >>= 1) pc += __shfl_down(pc, d, 64);
    __shared__ int wsum[4];
    if (lane == 0) wsum[wv] = pc;
    __syncthreads();
    if (tid == 0) counts[chunk] = wsum[0] + wsum[1] + wsum[2] + wsum[3];
}

// ---------------- Kernel 2: ordered compaction + tail fill -----------------
// One block per chunk. Each block reads the 8 KB counts array (L2-hot) once:
// masked reduce -> its exclusive prefix; full reduce -> grand total (for the
// -1 tail, filled in slices; all writes disjoint from the scatter).
__global__ __launch_bounds__(256) void compact(const uint32_t* __restrict__ bitmask,
                                               const int* __restrict__ counts,
                                               int* __restrict__ out_h,
                                               int* __restrict__ out_w) {
    const int chunk = (int)blockIdx.x;
    const int tid   = threadIdx.x;
    const int lane  = tid & 63, wv = tid >> 6;

    // counts[8t .. 8t+7] per thread
    const uint4 ca = ((const uint4*)counts)[2 * tid];
    const uint4 cb = ((const uint4*)counts)[2 * tid + 1];
    const int i0 = tid * 8;
    int contrib = 0, full = 0;
    {
        const uint32_t cv[8] = {ca.x, ca.y, ca.z, ca.w, cb.x, cb.y, cb.z, cb.w};
#pragma unroll
        for (int j = 0; j < 8; ++j) {
            full += (int)cv[j];
            contrib += (i0 + j < chunk) ? (int)cv[j] : 0;
        }
    }

    int rA = contrib, rB = full;
#pragma unroll
    for (int d = 32; d >= 1; d >>= 1) {
        rA += __shfl_down(rA, d, 64);
        rB += __shfl_down(rB, d, 64);
    }
    __shared__ int wsA[4], wsB[4], wscan[4];
    if (lane == 0) { wsA[wv] = rA; wsB[wv] = rB; }

    // this chunk's mask: 512 dwords, 2 per thread
    const uint2 m = ((const uint2*)(bitmask + (size_t)chunk * BLK_WORDS))[tid];
    const int pc = __popc(m.x) + __popc(m.y);

    int incl = pc;
#pragma unroll
    for (int d = 1; d < 64; d <<= 1) {
        int n = __shfl_up(incl, d, 64);
        if (lane >= d) incl += n;
    }
    if (lane == 63) wscan[wv] = incl;
    __syncthreads();

    const int chunk_base = wsA[0] + wsA[1] + wsA[2] + wsA[3];
    int total = wsB[0] + wsB[1] + wsB[2] + wsB[3];
    if (total > MAXK) total = MAXK;
    int wbase = 0;
    for (int i = 0; i < wv; ++i) wbase += wscan[i];

    const int h0 = (chunk & (NSTRIPS - 1)) * R;
    int off = chunk_base + wbase + (incl - pc);

    // ordered scatter
    uint32_t words[2] = {m.x, m.y};
    const uint32_t local0 = (uint32_t)tid * 64u;  // tid*2 dwords * 32 bits
#pragma unroll
    for (int wj = 0; wj < 2; ++wj) {
        uint32_t mm = words[wj];
        const uint32_t lb = local0 + (uint32_t)wj * 32u;
        while (mm) {
            const int bit = __ffs(mm) - 1;
            mm &= mm - 1;
            const uint32_t L = lb + (uint32_t)bit;  // bit index within chunk
            if (off < MAXK) {
                out_h[off] = h0 + (int)(L >> 11);
                out_w[off] = (int)(L & 2047u);
            }
            ++off;
        }
    }

    // -1 tail fill: this block's slice of [total, MAXK) in both planes
    const int i4base = chunk * TAIL_PER_BLK;
    for (int t = tid; t < TAIL_PER_BLK; t += 256) {
        const int i4 = i4base + t;
        if (i4 >= TAIL_I4) break;
        const int base = i4 * 4;
        if (base + 4 <= total) continue;  // fully covered by scatter
        if (base >= total) {
            const int4 neg = make_int4(-1, -1, -1, -1);
            *(int4*)(out_h + base) = neg;
            *(int4*)(out_w + base) = neg;
        } else {
#pragma unroll
            for (int j = 0; j < 4; ++j) {
                const int idx = base + j;
                if (idx >= total) { out_h[idx] = -1; out_w[idx] = -1; }
            }
        }
    }
}

extern "C" void kernel_launch(void* const* d_in, const int* in_sizes, int n_in,
                              void* d_out, int out_size, void* d_ws, size_t ws_size,
                              hipStream_t stream) {
    const float* scores = (const float*)d_in[0];
    int* out = (int*)d_out;

    uint32_t* bitmask = (uint32_t*)d_ws;                               // 4 MB
    int* counts = (int*)((char*)d_ws + (size_t)NBLK * BLK_WORDS * 4);  // NBLK ints

    nms_mask<<<NBLK, 256, 0, stream>>>(scores, (uint8_t*)bitmask, counts);
    compact<<<NBLK, 256, 0, stream>>>(bitmask, counts, out, out + MAXK);
}